// Round 2
// baseline (821.031 us; speedup 1.0000x reference)
//
#include <hip/hip_runtime.h>
#include <hip/hip_fp16.h>

namespace {
constexpr int Bn = 64;
constexpr int Tn = 1024;
constexpr int Kn = 256;

typedef _Float16 half8 __attribute__((ext_vector_type(8)));
typedef float f32x4 __attribute__((ext_vector_type(4)));

// ---- DPP wave-64 reductions ----
template <int C>
__device__ __forceinline__ float dppmax1(float x) {
    int o = __builtin_bit_cast(int, x);
    int y = __builtin_amdgcn_update_dpp(o, o, C, 0xF, 0xF, false);
    return fmaxf(x, __builtin_bit_cast(float, y));
}
template <int C>
__device__ __forceinline__ float dppadd1(float x) {
    int y = __builtin_amdgcn_update_dpp(0, __builtin_bit_cast(int, x), C, 0xF, 0xF, true);
    return x + __builtin_bit_cast(float, y);
}
// full 64-lane max (used where values are not replicated)
__device__ __forceinline__ float wave_max64(float x) {
    x = dppmax1<0x111>(x);
    x = dppmax1<0x112>(x);
    x = dppmax1<0x114>(x);
    x = dppmax1<0x118>(x);
    x = dppmax1<0x142>(x);  // row_bcast:15
    x = dppmax1<0x143>(x);  // row_bcast:31
    return __builtin_bit_cast(float,
        __builtin_amdgcn_readlane(__builtin_bit_cast(int, x), 63));
}
// max over a wave whose values are 4-fold replicated across 16-lane rows:
// row-local reduce (4 dep DPP) then readlane(0). Saves 2 DPP vs wave_max64.
__device__ __forceinline__ float wave_max16rep(float x) {
    x = dppmax1<0x111>(x);  // row_shr:1
    x = dppmax1<0x112>(x);  // row_shr:2
    x = dppmax1<0x114>(x);  // row_shr:4
    x = dppmax1<0x118>(x);  // row_shr:8
    return __builtin_bit_cast(float,
        __builtin_amdgcn_readlane(__builtin_bit_cast(int, x), 0));
}
__device__ __forceinline__ float wave_sum64(float x) {
    x = dppadd1<0x111>(x);
    x = dppadd1<0x112>(x);
    x = dppadd1<0x114>(x);
    x = dppadd1<0x118>(x);
    x = dppadd1<0x142>(x);
    x = dppadd1<0x143>(x);
    return __builtin_bit_cast(float,
        __builtin_amdgcn_readlane(__builtin_bit_cast(int, x), 63));
}

// ---- pre-kernel: exp(trans) in B-fragment order for the 16-wave layout ----
// wave w (0..15) owns columns n = 16w + (l&15); B[k][n] with
// k = 32*kt + (l>>4)*8 + i. Flat half8 index g = (w*8 + kt)*64 + l.
__global__ __launch_bounds__(256) void efrag_kernel(
    const float* __restrict__ trans, _Float16* __restrict__ efrag)
{
    const int g  = blockIdx.x * 256 + threadIdx.x;   // 0..8191
    const int l  = g & 63;
    const int kt = (g >> 6) & 7;
    const int w  = g >> 9;                           // 0..15
    const int n  = 16 * w + (l & 15);
    const int k0 = 32 * kt + (l >> 4) * 8;
    half8 hb;
#pragma unroll
    for (int i = 0; i < 8; ++i)
        hb[i] = (_Float16)__expf(trans[(k0 + i) * Kn + n]);
    ((half8*)efrag)[g] = hb;
}

// ---- one forward step; PB/NB compile-time ping-pong ----
template <int PB, int NB, bool MASKED>
__device__ __forceinline__ void step_fn(
    int tcur, float& alpha, float& R_prev,
    float& lg1, float& lg2, float& lg3,
    const float* __restrict__ in_b, int j_own, int La, int w, int l,
    const half8 (&Bfrag)[8],
    _Float16 (*__restrict__ p_sh)[Kn], float (*__restrict__ Mv)[16],
    const int* __restrict__ mask_sh)
{
    // drain LDS writes (p, Mv) then raw barrier; global prefetches stay in flight
    asm volatile("s_waitcnt lgkmcnt(0)" ::: "memory");
    __builtin_amdgcn_s_barrier();
    __builtin_amdgcn_sched_barrier(0);

    // rotate emission prefetch; issue next load early
    const float lgC = lg1; lg1 = lg2; lg2 = lg3;
    const int tp3 = (tcur + 3 < Tn) ? (tcur + 3) : (Tn - 1);
    lg3 = in_b[(size_t)tp3 * Kn + j_own];

    int mkC = 1;
    if (MASKED) mkC = mask_sh[tcur];

    // R_next = max_j alpha(t-1): tree over 16 per-wave maxima (off MFMA chain)
    const f32x4 m0 = *(const f32x4*)(&Mv[PB][0]);
    const f32x4 m1 = *(const f32x4*)(&Mv[PB][4]);
    const f32x4 m2 = *(const f32x4*)(&Mv[PB][8]);
    const f32x4 m3 = *(const f32x4*)(&Mv[PB][12]);
    const float R_next =
        fmaxf(fmaxf(fmaxf(fmaxf(m0[0], m0[1]), fmaxf(m0[2], m0[3])),
                    fmaxf(fmaxf(m1[0], m1[1]), fmaxf(m1[2], m1[3]))),
              fmaxf(fmaxf(fmaxf(m2[0], m2[1]), fmaxf(m2[2], m2[3])),
                    fmaxf(fmaxf(m3[0], m3[1]), fmaxf(m3[2], m3[3]))));

    // A-fragments of replicated p: lane reads p[32kt + La*8 .. +7]
    const half8* prow = (const half8*)(&p_sh[PB][0]);
    half8 af[8];
#pragma unroll
    for (int kt = 0; kt < 8; ++kt) af[kt] = prow[kt * 4 + La];

    // 2 independent accumulator chains (depth 4), full K=256, 1 N-tile
    f32x4 aA = {0.f, 0.f, 0.f, 0.f};
    f32x4 aB = {0.f, 0.f, 0.f, 0.f};
    __builtin_amdgcn_s_setprio(1);
#pragma unroll
    for (int kt = 0; kt < 8; kt += 2) {
        aA = __builtin_amdgcn_mfma_f32_16x16x32_f16(af[kt],     Bfrag[kt],     aA, 0, 0, 0);
        aB = __builtin_amdgcn_mfma_f32_16x16x32_f16(af[kt + 1], Bfrag[kt + 1], aB, 0, 0, 0);
    }
    __builtin_amdgcn_s_setprio(0);

    // D rows replicated: acc[0] = s for col (l&15) of this wave's tile
    const float s = aA[0] + aB[0];

    const float na = R_prev + __logf(s) + lgC;
    if (!MASKED || mkC > 0) alpha = na;

    // publish p(t) with delayed scale; record wave max for next step
    const float pv = __expf(fminf(alpha - R_next, 11.0f));
    if (l < 16) p_sh[NB][j_own] = (_Float16)pv;
    const float wmx = wave_max16rep(alpha);  // alphas 4-fold replicated
    Mv[NB][w] = wmx;                         // same value from all lanes

    R_prev = R_next;
}

template <bool MASKED>
__device__ __forceinline__ float run_chain(
    float alpha, float R_prev, float lg1, float lg2, float lg3,
    const float* __restrict__ in_b, int j_own, int La, int w, int l,
    const half8 (&Bfrag)[8],
    _Float16 (*__restrict__ p_sh)[Kn], float (*__restrict__ Mv)[16],
    const int* __restrict__ mask_sh)
{
    step_fn<0, 1, MASKED>(1, alpha, R_prev, lg1, lg2, lg3, in_b, j_own, La, w, l,
                          Bfrag, p_sh, Mv, mask_sh);
    for (int t = 2; t < Tn; t += 2) {
        step_fn<1, 0, MASKED>(t,     alpha, R_prev, lg1, lg2, lg3, in_b, j_own, La, w, l,
                              Bfrag, p_sh, Mv, mask_sh);
        step_fn<0, 1, MASKED>(t + 1, alpha, R_prev, lg1, lg2, lg3, in_b, j_own, La, w, l,
                              Bfrag, p_sh, Mv, mask_sh);
    }
    return alpha;
}

__global__ __launch_bounds__(1024) void crf_kernel(
    const float* __restrict__ inputs,     // (B,T,K)
    const long long* __restrict__ tags,   // (B,T)
    const int* __restrict__ mask,         // (B,T)
    const _Float16* __restrict__ efrag,   // precomputed exp(trans) fragments (or null)
    const float* __restrict__ trans,      // (K,K)
    const float* __restrict__ start_t,    // (K,)
    const float* __restrict__ end_t,      // (K,)
    float* __restrict__ out)              // scalar
{
    const int b   = blockIdx.x;
    const int tid = threadIdx.x;
    const int w   = tid >> 6;       // wave 0..15, owns columns [16w, 16w+16)
    const int l   = tid & 63;
    const int La  = l >> 4;         // k-slice group 0..3
    const int lc  = l & 15;
    const int j_own = 16 * w + lc;  // each j held by 4 lanes (replicated)

    __shared__ __align__(16) _Float16 p_sh[2][Kn];
    __shared__ __align__(16) float Mv[2][16];
    __shared__ int   mask_sh[Tn];
    __shared__ float red[16][2];
    __shared__ float sh_np;
    __shared__ int   sh_len;

    if (tid == 0) { sh_len = 0; sh_np = 0.f; }

    // ---- stage mask row in LDS + count length (1024 threads: one t each)
    const int mloc = mask[b * Tn + tid];
    mask_sh[tid] = mloc;
    __syncthreads();
    {
        const float cf = wave_sum64((float)((mloc > 0) ? 1 : 0));
        if (l == 0) atomicAdd(&sh_len, (int)(cf + 0.5f));
    }

    // ---- load E fragments (coalesced f16) or compute fallback
    half8 Bfrag[8];
    if (efrag != nullptr) {
        const half8* ef = (const half8*)efrag;
#pragma unroll
        for (int kt = 0; kt < 8; ++kt)
            Bfrag[kt] = ef[(w * 8 + kt) * 64 + l];
    } else {
        const int n  = j_own;
#pragma unroll
        for (int kt = 0; kt < 8; ++kt) {
            const int k0 = 32 * kt + La * 8;
            half8 hb;
#pragma unroll
            for (int i = 0; i < 8; ++i)
                hb[i] = (_Float16)__expf(trans[(k0 + i) * Kn + n]);
            Bfrag[kt] = hb;
        }
    }

    const size_t bTK = (size_t)b * (size_t)(Tn * Kn);
    const float* in_b = inputs + bTK;
    const float endj  = end_t[j_own];

    // alpha(0): end_transitions deferred to the final LSE (alpha frozen past
    // end_idx, so adding end_t at the end is mathematically identical)
    float alpha = in_b[j_own] + start_t[j_own];

    // 3-deep emission prefetch
    float lg1 = in_b[1 * Kn + j_own];
    float lg2 = in_b[2 * Kn + j_own];
    float lg3 = in_b[3 * Kn + j_own];

    // ---- pre-loop: block max of alpha(0) -> scale for p(0)
    {
        const float wmx = wave_max16rep(alpha);
        Mv[0][w] = wmx;
    }
    __syncthreads();
    const int end_idx = sh_len - 1;
    float R_prev;
    {
        const f32x4 m0 = *(const f32x4*)(&Mv[0][0]);
        const f32x4 m1 = *(const f32x4*)(&Mv[0][4]);
        const f32x4 m2 = *(const f32x4*)(&Mv[0][8]);
        const f32x4 m3 = *(const f32x4*)(&Mv[0][12]);
        R_prev =
            fmaxf(fmaxf(fmaxf(fmaxf(m0[0], m0[1]), fmaxf(m0[2], m0[3])),
                        fmaxf(fmaxf(m1[0], m1[1]), fmaxf(m1[2], m1[3]))),
                  fmaxf(fmaxf(fmaxf(m2[0], m2[1]), fmaxf(m2[2], m2[3])),
                        fmaxf(fmaxf(m3[0], m3[1]), fmaxf(m3[2], m3[3]))));
        const float pv = __expf(fminf(alpha - R_prev, 11.0f));
        if (l < 16) p_sh[0][j_own] = (_Float16)pv;
    }

    // ---- forward recursion (specialize away mask when all-valid)
    if (sh_len == Tn) {
        alpha = run_chain<false>(alpha, R_prev, lg1, lg2, lg3, in_b, j_own, La, w, l,
                                 Bfrag, p_sh, Mv, mask_sh);
    } else {
        alpha = run_chain<true>(alpha, R_prev, lg1, lg2, lg3, in_b, j_own, La, w, l,
                                Bfrag, p_sh, Mv, mask_sh);
    }

    // ---- denominator = logsumexp over 256 alphas (+ end_t, deferred)
    {
        const float av = alpha + endj;
        const float wm = wave_max16rep(av);
        const float ex = (l < 16) ? __expf(av - wm) : 0.f;
        const float sw = wave_sum64(ex);
        red[w][0] = wm;
        red[w][1] = sw;
    }

    // ---- numerator (gather path score); 1024 threads: one t each
    {
        float np;
        const int t  = tid;
        const int tg = (int)tags[b * Tn + t];
        const float e = in_b[(size_t)t * Kn + tg];
        if (t == 0) {
            np = e + start_t[tg];
        } else {
            const float mf = (float)mloc;
            const int   tq = (int)tags[b * Tn + t - 1];
            np = mf * (e + trans[tq * Kn + tg]);
        }
        np = wave_sum64(np);
        if (l == 0) atomicAdd(&sh_np, np);
    }
    __syncthreads();

    if (tid == 0) {
        float Rf = red[0][0];
#pragma unroll
        for (int q = 1; q < 16; ++q) Rf = fmaxf(Rf, red[q][0]);
        float S = 0.f;
#pragma unroll
        for (int q = 0; q < 16; ++q) S += red[q][1] * __expf(red[q][0] - Rf);
        const float denom = Rf + __logf(S);
        const float numer = sh_np + end_t[(int)tags[b * Tn + end_idx]];
        atomicAdd(out, numer - denom);
    }
}

}  // namespace

extern "C" void kernel_launch(void* const* d_in, const int* in_sizes, int n_in,
                              void* d_out, int out_size, void* d_ws, size_t ws_size,
                              hipStream_t stream) {
    const float*     inputs  = (const float*)d_in[0];
    const long long* tags    = (const long long*)d_in[1];
    const int*       mask    = (const int*)d_in[2];
    const float*     trans   = (const float*)d_in[3];
    const float*     start_t = (const float*)d_in[4];
    const float*     end_t   = (const float*)d_in[5];
    float* out = (float*)d_out;

    const size_t efrag_bytes = (size_t)Kn * Kn * sizeof(_Float16);  // 128 KiB
    const bool useEf = (d_ws != nullptr) && (ws_size >= efrag_bytes);

    hipMemsetAsync(out, 0, sizeof(float), stream);
    if (useEf) {
        efrag_kernel<<<dim3((Kn * Kn / 8) / 256), dim3(256), 0, stream>>>(
            trans, (_Float16*)d_ws);
    }
    crf_kernel<<<dim3(Bn), dim3(1024), 0, stream>>>(
        inputs, tags, mask, useEf ? (const _Float16*)d_ws : nullptr,
        trans, start_t, end_t, out);
}

// Round 4
// 613.693 us; speedup vs baseline: 1.3379x; 1.3379x over previous
//
#include <hip/hip_runtime.h>
#include <hip/hip_fp16.h>

namespace {
constexpr int Bn = 64;
constexpr int Tn = 1024;
constexpr int Kn = 256;

constexpr float LOG2E  = 1.4426950408889634f;
constexpr float LN2    = 0.6931471805599453f;
constexpr float RBIAS  = 4.0f;   // headroom: p = exp2(alpha2 - (max2 + RBIAS))
constexpr float PCLAMP = 15.5f;  // f16 overflow guard (2^15.5 < 65504)

typedef _Float16 half8 __attribute__((ext_vector_type(8)));
typedef float f32x4 __attribute__((ext_vector_type(4)));

// hardware base-2 transcendentals (v_exp_f32 / v_log_f32 ARE base-2 on gfx9)
__device__ __forceinline__ float fexp2(float x) {
    float r; asm("v_exp_f32 %0, %1" : "=v"(r) : "v"(x)); return r;
}
__device__ __forceinline__ float flog2(float x) {
    float r; asm("v_log_f32 %0, %1" : "=v"(r) : "v"(x)); return r;
}

// ---- DPP wave-64 reductions ----
template <int C>
__device__ __forceinline__ float dppmax1(float x) {
    int o = __builtin_bit_cast(int, x);
    int y = __builtin_amdgcn_update_dpp(o, o, C, 0xF, 0xF, false);
    return fmaxf(x, __builtin_bit_cast(float, y));
}
template <int C>
__device__ __forceinline__ float dppadd1(float x) {
    int y = __builtin_amdgcn_update_dpp(0, __builtin_bit_cast(int, x), C, 0xF, 0xF, true);
    return x + __builtin_bit_cast(float, y);
}
// max over a wave whose per-column values are duplicated between lanes l and l+32:
// reduce lanes 0..31 only (4 shr + bcast15), result at lane 31.
__device__ __forceinline__ float wave_max32rep(float x) {
    x = dppmax1<0x111>(x);
    x = dppmax1<0x112>(x);
    x = dppmax1<0x114>(x);
    x = dppmax1<0x118>(x);
    x = dppmax1<0x142>(x);  // row_bcast:15
    return __builtin_bit_cast(float,
        __builtin_amdgcn_readlane(__builtin_bit_cast(int, x), 31));
}
__device__ __forceinline__ float wave_sum64(float x) {
    x = dppadd1<0x111>(x);
    x = dppadd1<0x112>(x);
    x = dppadd1<0x114>(x);
    x = dppadd1<0x118>(x);
    x = dppadd1<0x142>(x);
    x = dppadd1<0x143>(x);
    return __builtin_bit_cast(float,
        __builtin_amdgcn_readlane(__builtin_bit_cast(int, x), 63));
}

// ---- pre-kernel: exp(trans) in B-fragment order (8-wave layout) ----
// wave w (0..7), tile c (0..1): cols n = 32w + 16c + (l&15);
// k = 32*kt + (l>>4)*8 + i. Flat half8 index g = ((w*2+c)*8+kt)*64 + l.
__global__ __launch_bounds__(256) void efrag_kernel(
    const float* __restrict__ trans, _Float16* __restrict__ efrag)
{
    const int g  = blockIdx.x * 256 + threadIdx.x;   // 0..8191
    const int l  = g & 63;
    const int kt = (g >> 6) & 7;
    const int c  = (g >> 9) & 1;
    const int w  = g >> 10;
    const int n  = 32 * w + 16 * c + (l & 15);
    const int k0 = 32 * kt + (l >> 4) * 8;
    half8 hb;
#pragma unroll
    for (int i = 0; i < 8; ++i)
        hb[i] = (_Float16)__expf(trans[(k0 + i) * Kn + n]);
    ((half8*)efrag)[g] = hb;
}

// ---- one forward step; PB/NB compile-time ping-pong ----
// Mv roles: READ Mv[NB] (max alpha(t-2), written at step t-1),
//           WRITE Mv[PB] (max alpha(t-1), reduced here, consumed at t+1).
template <int PB, int NB, bool MASKED>
__device__ __forceinline__ void step_fn(
    int tcur, float& alpha, float& R_prev,
    float& lg1, float& lg2, float& lg3,
    const float* __restrict__ in_b, int j_own, int La, int w, int l,
    const half8 (&Bfrag)[2][8], const f32x4 zacc,
    _Float16 (*__restrict__ p_sh)[Kn], float (*__restrict__ Mv)[8],
    const int* __restrict__ mask_sh)
{
    // drain LDS ops then raw barrier; global prefetches stay in flight
    asm volatile("s_waitcnt lgkmcnt(0)" ::: "memory");
    __builtin_amdgcn_s_barrier();
    __builtin_amdgcn_sched_barrier(0);

    // A-fragment reads first (LDS latency head start)
    const half8* prow = (const half8*)(&p_sh[PB][0]);
    half8 af[8];
#pragma unroll
    for (int kt = 0; kt < 8; ++kt) af[kt] = prow[kt * 4 + La];

    // Mv tree loads (same-address broadcast, free)
    const f32x4 m0 = *(const f32x4*)(&Mv[NB][0]);
    const f32x4 m1 = *(const f32x4*)(&Mv[NB][4]);

    // deferred max: reduce alpha(t-1) now (hides under af latency), for step t+1
    const float wmx = wave_max32rep(alpha);
    Mv[PB][w] = wmx;   // all lanes, same addr+data (benign)

    // emission prefetch rotate; issue next load early
    const float lgC = lg1; lg1 = lg2; lg2 = lg3;
    const int tp3 = (tcur + 3 < Tn) ? (tcur + 3) : (Tn - 1);
    lg3 = in_b[(size_t)tp3 * Kn + j_own];

    int mkC = 1;
    if (MASKED) mkC = mask_sh[tcur];

    // scale for publishing p(t): max alpha(t-2) + bias
    const float R_use =
        fmaxf(fmaxf(fmaxf(m0[0], m0[1]), fmaxf(m0[2], m0[3])),
              fmaxf(fmaxf(m1[0], m1[1]), fmaxf(m1[2], m1[3]))) + RBIAS;

    // 4 independent MFMA chains; first MFMA of each consumes pinned zero C
    __builtin_amdgcn_s_setprio(1);
    f32x4 a0a = __builtin_amdgcn_mfma_f32_16x16x32_f16(af[0], Bfrag[0][0], zacc, 0, 0, 0);
    f32x4 a1a = __builtin_amdgcn_mfma_f32_16x16x32_f16(af[0], Bfrag[1][0], zacc, 0, 0, 0);
    f32x4 a0b = __builtin_amdgcn_mfma_f32_16x16x32_f16(af[1], Bfrag[0][1], zacc, 0, 0, 0);
    f32x4 a1b = __builtin_amdgcn_mfma_f32_16x16x32_f16(af[1], Bfrag[1][1], zacc, 0, 0, 0);
#pragma unroll
    for (int kt = 2; kt < 8; kt += 2) {
        a0a = __builtin_amdgcn_mfma_f32_16x16x32_f16(af[kt],     Bfrag[0][kt],     a0a, 0, 0, 0);
        a1a = __builtin_amdgcn_mfma_f32_16x16x32_f16(af[kt],     Bfrag[1][kt],     a1a, 0, 0, 0);
        a0b = __builtin_amdgcn_mfma_f32_16x16x32_f16(af[kt + 1], Bfrag[0][kt + 1], a0b, 0, 0, 0);
        a1b = __builtin_amdgcn_mfma_f32_16x16x32_f16(af[kt + 1], Bfrag[1][kt + 1], a1b, 0, 0, 0);
    }
    __builtin_amdgcn_s_setprio(0);

    const float s = (La & 1) ? (a1a[0] + a1b[0]) : (a0a[0] + a0b[0]);

    // base-2 recursion: alpha2(t) = R_prev + log2(s) + lg*log2e
    const float na = R_prev + flog2(s) + lgC * LOG2E;
    if (!MASKED || mkC > 0) alpha = na;

    const float pv = fexp2(fminf(alpha - R_use, PCLAMP));
    if (l < 32) p_sh[NB][j_own] = (_Float16)pv;

    R_prev = R_use;
}

template <bool MASKED>
__device__ __forceinline__ float run_chain(
    float alpha, float R_prev, float lg1, float lg2, float lg3,
    const float* __restrict__ in_b, int j_own, int La, int w, int l,
    const half8 (&Bfrag)[2][8],
    _Float16 (*__restrict__ p_sh)[Kn], float (*__restrict__ Mv)[8],
    const int* __restrict__ mask_sh)
{
    // pinned zero accumulator: lives in 4 VGPRs for the whole loop,
    // consumed as the C operand of each chain's first MFMA (no per-step movs)
    f32x4 zacc = {0.f, 0.f, 0.f, 0.f};
    asm volatile("" : "+v"(zacc));

    step_fn<0, 1, MASKED>(1, alpha, R_prev, lg1, lg2, lg3, in_b, j_own, La, w, l,
                          Bfrag, zacc, p_sh, Mv, mask_sh);
    for (int t = 2; t < Tn; t += 2) {
        step_fn<1, 0, MASKED>(t,     alpha, R_prev, lg1, lg2, lg3, in_b, j_own, La, w, l,
                              Bfrag, zacc, p_sh, Mv, mask_sh);
        step_fn<0, 1, MASKED>(t + 1, alpha, R_prev, lg1, lg2, lg3, in_b, j_own, La, w, l,
                              Bfrag, zacc, p_sh, Mv, mask_sh);
    }
    return alpha;
}

__global__ __launch_bounds__(512) void crf_kernel(
    const float* __restrict__ inputs,     // (B,T,K)
    const long long* __restrict__ tags,   // (B,T)
    const int* __restrict__ mask,         // (B,T)
    const _Float16* __restrict__ efrag,   // precomputed exp(trans) fragments (or null)
    const float* __restrict__ trans,      // (K,K)
    const float* __restrict__ start_t,    // (K,)
    const float* __restrict__ end_t,      // (K,)
    float* __restrict__ out)              // scalar
{
    const int b   = blockIdx.x;
    const int tid = threadIdx.x;
    const int w   = tid >> 6;       // wave 0..7, owns cols [32w, 32w+32)
    const int l   = tid & 63;
    const int La  = l >> 4;
    const int lc  = l & 15;
    const int j_own = 32 * w + 16 * (La & 1) + lc;  // dup on lanes l, l+32

    __shared__ __align__(16) _Float16 p_sh[2][Kn];
    __shared__ __align__(16) float Mv[2][8];
    __shared__ int   mask_sh[Tn];
    __shared__ float red[8][2];
    __shared__ float sh_np;
    __shared__ int   sh_len;

    if (tid == 0) { sh_len = 0; sh_np = 0.f; }

    // ---- stage mask row in LDS + count length
    int cnt = 0;
    for (int t = tid; t < Tn; t += 512) {
        const int m = mask[b * Tn + t];
        mask_sh[t] = m;
        cnt += (m > 0) ? 1 : 0;
    }
    __syncthreads();
    {
        const float cf = wave_sum64((float)cnt);
        if (l == 0) atomicAdd(&sh_len, (int)(cf + 0.5f));
    }

    // ---- load E fragments (coalesced f16) or compute fallback
    half8 Bfrag[2][8];
    if (efrag != nullptr) {
        const half8* ef = (const half8*)efrag;
#pragma unroll
        for (int c = 0; c < 2; ++c)
#pragma unroll
            for (int kt = 0; kt < 8; ++kt)
                Bfrag[c][kt] = ef[((w * 2 + c) * 8 + kt) * 64 + l];
    } else {
#pragma unroll
        for (int c = 0; c < 2; ++c) {
            const int n = 32 * w + 16 * c + lc;
#pragma unroll
            for (int kt = 0; kt < 8; ++kt) {
                const int k0 = 32 * kt + La * 8;
                half8 hb;
#pragma unroll
                for (int i = 0; i < 8; ++i)
                    hb[i] = (_Float16)__expf(trans[(k0 + i) * Kn + n]);
                Bfrag[c][kt] = hb;
            }
        }
    }

    const size_t bTK = (size_t)b * (size_t)(Tn * Kn);
    const float* in_b = inputs + bTK;
    const float endj  = end_t[j_own];

    // alpha in BASE-2 units; end_transitions deferred to the final LSE
    float alpha = (in_b[j_own] + start_t[j_own]) * LOG2E;

    // 3-deep emission prefetch (raw natural-log floats; *LOG2E applied at use)
    float lg1 = in_b[1 * Kn + j_own];
    float lg2 = in_b[2 * Kn + j_own];
    float lg3 = in_b[3 * Kn + j_own];

    // ---- prologue: seed Mv[1] with per-wave max of alpha(0); publish p(0)
    {
        const float wmx = wave_max32rep(alpha);
        Mv[1][w] = wmx;
    }
    __syncthreads();
    const int end_idx = sh_len - 1;
    float R_prev;
    {
        const f32x4 m0 = *(const f32x4*)(&Mv[1][0]);
        const f32x4 m1 = *(const f32x4*)(&Mv[1][4]);
        R_prev = fmaxf(fmaxf(fmaxf(m0[0], m0[1]), fmaxf(m0[2], m0[3])),
                       fmaxf(fmaxf(m1[0], m1[1]), fmaxf(m1[2], m1[3]))) + RBIAS;
        const float pv = fexp2(fminf(alpha - R_prev, PCLAMP));
        if (l < 32) p_sh[0][j_own] = (_Float16)pv;
    }

    // ---- forward recursion (specialize away mask when all-valid)
    if (sh_len == Tn) {
        alpha = run_chain<false>(alpha, R_prev, lg1, lg2, lg3, in_b, j_own, La, w, l,
                                 Bfrag, p_sh, Mv, mask_sh);
    } else {
        alpha = run_chain<true>(alpha, R_prev, lg1, lg2, lg3, in_b, j_own, La, w, l,
                                Bfrag, p_sh, Mv, mask_sh);
    }

    // ---- denominator = ln2 * logsumexp2 over 256 alpha2 (+ end_t, deferred)
    {
        const float av = alpha + endj * LOG2E;
        const float wm = wave_max32rep(av);
        const float ex = (l < 32) ? fexp2(av - wm) : 0.f;
        const float sw = wave_sum64(ex);
        red[w][0] = wm;
        red[w][1] = sw;
    }

    // ---- numerator (gather path score, natural units)
    float np = 0.f;
    for (int t = tid; t < Tn; t += 512) {
        const int   tg = (int)tags[b * Tn + t];
        const float e  = in_b[(size_t)t * Kn + tg];
        if (t == 0) {
            np += e + start_t[tg];
        } else {
            const float mf = (float)mask_sh[t];
            const int   tq = (int)tags[b * Tn + t - 1];
            np += mf * (e + trans[tq * Kn + tg]);
        }
    }
    np = wave_sum64(np);
    if (l == 0) atomicAdd(&sh_np, np);
    __syncthreads();

    if (tid == 0) {
        float Rf = red[0][0];
#pragma unroll
        for (int q = 1; q < 8; ++q) Rf = fmaxf(Rf, red[q][0]);
        float S = 0.f;
#pragma unroll
        for (int q = 0; q < 8; ++q) S += red[q][1] * fexp2(red[q][0] - Rf);
        const float denom = LN2 * (Rf + flog2(S));
        const float numer = sh_np + end_t[(int)tags[b * Tn + end_idx]];
        atomicAdd(out, numer - denom);
    }
}

}  // namespace

extern "C" void kernel_launch(void* const* d_in, const int* in_sizes, int n_in,
                              void* d_out, int out_size, void* d_ws, size_t ws_size,
                              hipStream_t stream) {
    const float*     inputs  = (const float*)d_in[0];
    const long long* tags    = (const long long*)d_in[1];
    const int*       mask    = (const int*)d_in[2];
    const float*     trans   = (const float*)d_in[3];
    const float*     start_t = (const float*)d_in[4];
    const float*     end_t   = (const float*)d_in[5];
    float* out = (float*)d_out;

    const size_t efrag_bytes = (size_t)Kn * Kn * sizeof(_Float16);  // 128 KiB
    const bool useEf = (d_ws != nullptr) && (ws_size >= efrag_bytes);

    (void)hipMemsetAsync(out, 0, sizeof(float), stream);
    if (useEf) {
        efrag_kernel<<<dim3((Kn * Kn / 8) / 256), dim3(256), 0, stream>>>(
            trans, (_Float16*)d_ws);
    }
    crf_kernel<<<dim3(Bn), dim3(512), 0, stream>>>(
        inputs, tags, mask, useEf ? (const _Float16*)d_ws : nullptr,
        trans, start_t, end_t, out);
}